// Round 13
// baseline (190.547 us; speedup 1.0000x reference)
//
#include <hip/hip_runtime.h>
#include <stdint.h>

typedef unsigned long long u64;
typedef unsigned int u32;

#define NUM_B 32
#define NUM_P 76800
#define TOPK 1500
#define NBINS 2048   // linear bins: bin = min(int(s*2048), 2047); ~37.5 scores/bin
#define CAP 2048
#define NWORDS 24    // ceil(1500/64) u64 words per mask row == number of 64-row tiles
#define NCHUNK 6     // ceil(1500/256) row chunks for mask grid
#define HSLICES 16   // private histogram slices per batch (no global atomics)
#define HCHUNK (NUM_P / HSLICES)   // 4800 priors per slice
#define PB 1984      // prefilter bin for candidate staging (score ~0.96875)
#define SCAP 512     // per-(batch,slice) stage capacity (expected ~150; overflow->fallback)

__device__ __forceinline__ u32 fbits(float f) { return __float_as_uint(f); }
// Monotone non-decreasing in s => threshold-bin selection is order-correct,
// and cross-bin key order == bin order (floor is monotone).
__device__ __forceinline__ int binOf(float s) {
    int b = (int)(s * (float)NBINS);
    return (b > NBINS - 1) ? NBINS - 1 : b;
}
// wave-uniform lane read of a u64 register
__device__ __forceinline__ u64 readlane64(u64 v, int l) {
    u32 lo = (u32)__builtin_amdgcn_readlane((int)(u32)(v & 0xffffffffu), l);
    u32 hi = (u32)__builtin_amdgcn_readlane((int)(u32)(v >> 32), l);
    return ((u64)hi << 32) | lo;
}

// ---------------- histogram + FUSED threshold ----------------
// LDS-private hist per (batch, slice); zeroes bucket ctrs; stages candidates with
// bin >= PB (compact's fast path).  v13: the LAST-ARRIVING block of each batch
// (device-scope counter + release/acquire fences) runs the threshold scan inline,
// eliminating the thresh_kernel launch boundary.  Scan code is verbatim thresh.
__global__ __launch_bounds__(256) void hist_kernel(const float4* __restrict__ conf4,
                                                   u32* __restrict__ hist,
                                                   u32* __restrict__ bpos,
                                                   u64* __restrict__ skey,
                                                   u32* __restrict__ scnt,
                                                   u32* __restrict__ done,
                                                   int* __restrict__ tbin,
                                                   u32* __restrict__ binbase,
                                                   u32* __restrict__ bincnt,
                                                   u32* __restrict__ ntotal) {
    int c = blockIdx.x, b = blockIdx.y, tid = threadIdx.x;
    // zero compact's per-(batch,bin) bucket counters: 2048/16 = 128 bins per block
    if (tid < NBINS / HSLICES) bpos[(size_t)b * NBINS + c * (NBINS / HSLICES) + tid] = 0;
    __shared__ u32 h[NBINS];
    __shared__ u64 stg[SCAP];
    __shared__ u32 sc_s;
    if (tid == 0) sc_s = 0;
    for (int i = tid; i < NBINS; i += 256) h[i] = 0;
    __syncthreads();
    const float4* base = conf4 + (size_t)b * (NUM_P / 2) + (size_t)c * (HCHUNK / 2);
    int pbase = c * HCHUNK;            // within-batch prior index base for this slice
    for (int i = tid; i < HCHUNK / 2; i += 256) {
        float4 v = base[i];            // 2 priors: (c0,c1,c0,c1); class-1 = .y/.w
        int p0 = pbase + i * 2;
        if (v.y > 0.01f) {
            int bn = binOf(v.y);
            atomicAdd(&h[bn], 1u);
            if (bn >= PB) {
                u32 s = atomicAdd(&sc_s, 1u);
                if (s < SCAP) stg[s] = ((u64)fbits(v.y) << 32) | (u32)(~p0);
            }
        }
        if (v.w > 0.01f) {
            int bn = binOf(v.w);
            atomicAdd(&h[bn], 1u);
            if (bn >= PB) {
                u32 s = atomicAdd(&sc_s, 1u);
                if (s < SCAP) stg[s] = ((u64)fbits(v.w) << 32) | (u32)(~(p0 + 1));
            }
        }
    }
    __syncthreads();
    u32* outp = hist + ((size_t)b * HSLICES + c) * NBINS;
    for (int i = tid; i < NBINS; i += 256) outp[i] = h[i];
    u32 n = sc_s;
    if (tid == 0) scnt[b * HSLICES + c] = n;   // raw (may exceed SCAP -> fallback)
    u64* sk = skey + (size_t)(b * HSLICES + c) * SCAP;
    u32 nn = (n < (u32)SCAP) ? n : (u32)SCAP;
    for (u32 i = tid; i < nn; i += 256) sk[i] = stg[i];

    // ---- fused threshold: last-arriving block of batch b runs the scan ----
    __shared__ u32 vals[256];
    __shared__ int s_min;
    __shared__ u32 s_tk;
    __syncthreads();                   // drain this block's global stores (hist/sk/scnt)
    if (tid == 0) {
        __threadfence();               // release: publish our slice device-wide
        s_tk = atomicAdd(&done[b], 1u);
    }
    __syncthreads();
    if (s_tk != HSLICES - 1) return;   // not last -> done (uniform branch)
    __threadfence();                   // acquire: all 16 slices now visible
    const u32* hb = hist + (size_t)b * HSLICES * NBINS;
    u32 total = 0;
    for (int ch = 0; ch < NBINS / 256; ++ch) {
        if (tid == 0) s_min = 256;
        int bin = NBINS - 1 - (ch * 256 + tid);
        u32 v = 0;
#pragma unroll
        for (int s = 0; s < HSLICES; ++s) v += hb[(size_t)s * NBINS + bin];
        __syncthreads();
        vals[tid] = v;
        __syncthreads();
        for (int off = 1; off < 256; off <<= 1) {
            u32 add = (tid >= off) ? vals[tid - off] : 0;
            __syncthreads();
            vals[tid] += add;
            __syncthreads();
        }
        u32 cum = total + vals[tid];          // inclusive suffix count down to `bin`
        binbase[(size_t)b * NBINS + bin] = cum - v;   // exclusive: bins strictly above
        bincnt [(size_t)b * NBINS + bin] = v;
        if (cum >= TOPK) atomicMin(&s_min, tid);
        __syncthreads();
        if (s_min < 256) {
            if (tid == s_min) { tbin[b] = bin; ntotal[b] = cum; }
            return;
        }
        total += vals[255];
    }
    if (tid == 0) { tbin[b] = 0; ntotal[b] = total; }
}

// ---------------- compact candidates into bin-grouped buckets ----------------
// Fast path (tbin >= PB, no stage overflow): read staged keys (~19 KB/batch) instead
// of re-scanning 19.7 MB of conf. Slow path: full conf scan (data-independent safety).
// keys land pre-grouped: bucket of bin bn occupies [binbase[bn], binbase[bn]+bincnt[bn]).
__global__ __launch_bounds__(256) void compact_kernel(
    const float4* __restrict__ conf4, const int* __restrict__ tbin,
    const u32* __restrict__ binbase, u32* __restrict__ bpos,
    u64* __restrict__ keys, const u64* __restrict__ skey,
    const u32* __restrict__ scnt) {
    int b = blockIdx.y;
    int tid = threadIdx.x;
    int tb = tbin[b];
    if (tb >= PB) {
        bool ovf = false;
#pragma unroll
        for (int s = 0; s < HSLICES; ++s) ovf |= (scnt[b * HSLICES + s] > (u32)SCAP);
        if (!ovf) {
            if (blockIdx.x >= HSLICES) return;
            int sl = blockIdx.x;
            u32 cnt = scnt[b * HSLICES + sl];
            const u64* sk = skey + (size_t)(b * HSLICES + sl) * SCAP;
            for (u32 i = tid; i < cnt; i += 256) {
                u64 key = sk[i];
                float sc = __uint_as_float((u32)(key >> 32));
                int bn = binOf(sc);
                if (bn >= tb) {
                    u32 slot = atomicAdd(&bpos[(size_t)b * NBINS + bn], 1u);
                    u32 pos = binbase[(size_t)b * NBINS + bn] + slot;
                    if (pos < CAP) keys[(size_t)b * CAP + pos] = key;
                }
            }
            return;
        }
    }
    // slow path: full conf scan
    int f4 = blockIdx.x * 256 + tid;            // float4 index within batch (2 priors)
    float4 c = conf4[(size_t)b * (NUM_P / 2) + f4];
    int p0 = f4 * 2, p1 = p0 + 1;
    int b0 = binOf(c.y);
    if (c.y > 0.01f && b0 >= tb) {
        u32 slot = atomicAdd(&bpos[(size_t)b * NBINS + b0], 1u);
        u32 pos = binbase[(size_t)b * NBINS + b0] + slot;
        if (pos < CAP) keys[(size_t)b * CAP + pos] = ((u64)fbits(c.y) << 32) | (u32)(~p0);
    }
    int b1 = binOf(c.w);
    if (c.w > 0.01f && b1 >= tb) {
        u32 slot = atomicAdd(&bpos[(size_t)b * NBINS + b1], 1u);
        u32 pos = binbase[(size_t)b * NBINS + b1] + slot;
        if (pos < CAP) keys[(size_t)b * CAP + pos] = ((u64)fbits(c.w) << 32) | (u32)(~p1);
    }
}

// ---------------- rank via bin base + small bucket scan, then gather+decode ----------
// rank(key) = binbase[bin(key)] + |{k in same bucket : k > key}|.  Cross-bin order is
// exact (bin order == score order; keys in higher bins are strictly greater).  Bucket
// is ~38 entries -> O(n * 38) total instead of O(n^2).  No LDS.
__global__ __launch_bounds__(256) void rank_decode_kernel(
    const u64* __restrict__ keys, const u32* __restrict__ binbase,
    const u32* __restrict__ bincnt, const u32* __restrict__ ntotal,
    const float* __restrict__ loc, const float* __restrict__ prior,
    float* __restrict__ sscore, float* __restrict__ sbox) {
#pragma clang fp contract(off)
    int b = blockIdx.y;
    int g = blockIdx.x * 256 + threadIdx.x;
    int n = (int)min(ntotal[b], (u32)CAP);
    if (g >= n) return;
    const u64* kb = keys + (size_t)b * CAP;
    u64 mykey = kb[g];
    float sc = __uint_as_float((u32)(mykey >> 32));
    int bn = binOf(sc);
    u32 start = binbase[(size_t)b * NBINS + bn];
    u32 end = start + bincnt[(size_t)b * NBINS + bn];
    if (end > (u32)n) end = (u32)n;
    u32 rank = start;
#pragma unroll 4
    for (u32 j = start; j < end; ++j) rank += (kb[j] > mykey) ? 1u : 0u;

    if (rank < TOPK) {
        u32 pidx = ~(u32)mykey;
        const float* lp = &loc[((size_t)b * NUM_P + pidx) * 4];
        const float* pp = &prior[(size_t)pidx * 4];
        float lx = lp[0], ly = lp[1], lw = lp[2], lh = lp[3];
        float pcx = pp[0], pcy = pp[1], pw = pp[2], ph = pp[3];
        float cx = pcx + (lx * 0.1f) * pw;
        float cy = pcy + (ly * 0.1f) * ph;
        float w  = pw * expf(lw * 0.2f);
        float h  = ph * expf(lh * 0.2f);
        float x1 = cx - w * 0.5f;
        float y1 = cy - h * 0.5f;
        float x2 = x1 + w;
        float y2 = y1 + h;
        sscore[(size_t)b * TOPK + rank] = sc;
        float* bx = &sbox[((size_t)b * TOPK + rank) * 4];
        bx[0] = x1; bx[1] = y1; bx[2] = x2; bx[3] = y2;
    }
}

// ---------------- NMS phase 1: suppression bitmask — transposed, balanced, div-free ----
// v10 layout: rows store words w > tile(i) as FORWARD suppression, and the diag
// slot (w == tile(i)) stores the BACKWARD column: bits j < i-in-word with
// iou(i,j) > thr.  By IoU symmetry C[l] bit i == forward M[i] bit l, so the sweep's
// ballot-walk over columns reproduces the exact greedy.  Slots with w < tile(i)
// remain unwritten and are provably never consumed.
__global__ __launch_bounds__(256) void mask_kernel(
    const float* __restrict__ sbox, u64* __restrict__ mask) {
#pragma clang fp contract(off)
    int w = blockIdx.x, c = blockIdx.y, b = blockIdx.z, tid = threadIdx.x;
    int i = c * 256 + tid;
    if ((w * 64 + 63) <= (c * 256)) return;   // whole chunk dead: no store at all
    __shared__ float4 cbox[64];
    __shared__ float car[64];
    if (tid < 64) {
        int j = w * 64 + tid;
        float4 bx = make_float4(0.f, 0.f, 0.f, 0.f);
        if (j < TOPK) bx = ((const float4*)sbox)[(size_t)b * TOPK + j];
        cbox[tid] = bx;
        car[tid] = (bx.z - bx.x) * (bx.w - bx.y);
    }
    __syncthreads();
    if (i < TOPK && (i >> 6) <= w) {
        const double MID = 0.5 * ((double)__uint_as_float(0x3E4CCCCDu) +
                                  (double)__uint_as_float(0x3E4CCCCEu));
        const float4 bx = ((const float4*)sbox)[(size_t)b * TOPK + i];
        float x1i = bx.x, y1i = bx.y, x2i = bx.z, y2i = bx.w;
        float ai = (x2i - x1i) * (y2i - y1i);
        u64 m = 0;
        for (int j2 = 0; j2 < 64; ++j2) {
            float4 cb = cbox[j2];
            float xx1 = fmaxf(cb.x, x1i);
            float yy1 = fmaxf(cb.y, y1i);
            float xx2 = fminf(cb.z, x2i);
            float yy2 = fminf(cb.w, y2i);
            float iw = fmaxf(xx2 - xx1, 0.0f);
            float ih = fmaxf(yy2 - yy1, 0.0f);
            float inter = iw * ih;
            float denom = (car[j2] + ai) - inter;
            if ((double)inter >= MID * (double)denom) m |= (1ULL << j2);
        }
        // diag word -> backward column (j < i in-word); off-diag (w > tile) -> full
        // word (all j there are > i globally).  (1<<0)-1 == 0 handles in-word row 0.
        u64 sel = ((i >> 6) == w) ? ((1ULL << (i - w * 64)) - 1ULL) : ~0ULL;
        mask[((size_t)b * NWORDS + w) * TOPK + i] = m & sel;
    }
}

// ---------------- NMS phase 2: producer/consumer sweep, one block (4 waves) per batch ----
// v10 sweep (measured best): wave 0 consumes from LDS; waves 1-3 stage 8 words
// each, triple-buffered, register-hop pipeline.  Greedy walk uses the BACKWARD
// column in the diag slot:
//   i = ffs(alive); kept |= bit i; alive &= ~bit i; alive &= ~ballot(col>>i & 1)
// — no per-iteration readlane of mask data.  Bit-exact greedy (IoU symmetry).
__global__ __launch_bounds__(256) void sweep_kernel(
    const u64* __restrict__ mask, const float* __restrict__ sscore,
    const float* __restrict__ sbox, float* __restrict__ out) {
    int b = blockIdx.x, tid = threadIdx.x;
    int lane = tid & 63, wid = tid >> 6;

    const u64* mbase = mask + (size_t)b * NWORDS * TOPK;   // word w, row r: mbase[w*TOPK+r]

    __shared__ u64 rowbuf[3][NWORDS][65];   // [slot][word][row(+pad)]
    __shared__ u64 aw[NWORDS];
    __shared__ u32 pfx[NWORDS + 1];

    u64 act = 0;
    u64 sv[8];
    if (wid == 0) {
        // initial active bitmap from validity (score > 0); lane w owns act word w
        for (int c = 0; c < NWORDS; ++c) {
            int r = c * 64 + lane;
            bool v = (r < TOPK) && (sscore[(size_t)b * TOPK + r] > 0.0f);
            u64 m = __ballot(v);
            if (lane == c) act = m;
        }
    } else {
        int w0 = (wid - 1) * 8;
        // stage tiles 0 and 1 (rows < 1500; only words w >= tile are valid in mem)
#pragma unroll
        for (int t = 0; t < 2; ++t) {
            u64 tmp[8];
#pragma unroll
            for (int k = 0; k < 8; ++k)
                tmp[k] = (w0 + k >= t) ? mbase[(size_t)(w0 + k) * TOPK + t * 64 + lane] : 0ULL;
#pragma unroll
            for (int k = 0; k < 8; ++k)
                rowbuf[t][w0 + k][lane] = tmp[k];
        }
        // issue loads for tile 2 into the register hop
        {
            int rr = 2 * 64 + lane;
#pragma unroll
            for (int k = 0; k < 8; ++k)
                sv[k] = (w0 + k >= 2) ? mbase[(size_t)(w0 + k) * TOPK + rr] : 0ULL;
        }
    }
    __syncthreads();

    for (int T = 0; T < NWORDS; ++T) {
        if (wid == 0) {
            // diag slot of tile T = BACKWARD column of row (T*64+lane)
            u64 col = rowbuf[T % 3][T][lane];
            u64 actw = readlane64(act, T);
            u64 alive = actw, kept = 0;
            while (alive) {
                int i2 = __ffsll(alive) - 1;
                kept |= (1ULL << i2);
                alive &= ~(1ULL << i2);
                u64 killm = __ballot(((col >> i2) & 1ULL) != 0ULL);
                alive &= ~killm;
            }
            if (lane == T) act = kept;
            // cross-tile apply: word lane of kept rows
            if (lane > T && lane < NWORDS) {
                u64 kb = kept;
                while (kb) {
                    int r = __ffsll(kb) - 1;
                    kb &= kb - 1;
                    act &= ~rowbuf[T % 3][lane][r];
                }
            }
        } else {
            int tw = T + 2;                 // tile whose data sits in sv (loaded last round)
            if (tw < NWORDS) {
                int w0 = (wid - 1) * 8;
#pragma unroll
                for (int k = 0; k < 8; ++k)
                    rowbuf[tw % 3][w0 + k][lane] = sv[k];
                int tn = T + 3;
                if (tn < NWORDS) {
                    int rr = tn * 64 + lane;
                    bool vr = rr < TOPK;
#pragma unroll
                    for (int k = 0; k < 8; ++k)
                        sv[k] = (vr && (w0 + k >= tn))
                                    ? mbase[(size_t)(w0 + k) * TOPK + rr] : 0ULL;
                }
            }
        }
        __syncthreads();
    }

    // epilogue: zero both output planes (exact float4 cover: 2*1500*5 = 15000 floats
    // = 3750 float4, base offset b*60000 B is 16B-aligned), then compact write
    if (wid == 0 && lane < NWORDS) aw[lane] = act;
    {
        float4* pz = (float4*)(out + (size_t)b * 2 * TOPK * 5);
        float4 z4 = make_float4(0.f, 0.f, 0.f, 0.f);
        for (int t = tid; t < (2 * TOPK * 5) / 4; t += 256) pz[t] = z4;
    }
    __syncthreads();
    if (tid == 0) {
        u32 acc = 0;
        for (int wd = 0; wd < NWORDS; ++wd) { pfx[wd] = acc; acc += (u32)__popcll(aw[wd]); }
        pfx[NWORDS] = acc;
    }
    __syncthreads();
    for (int r = tid; r < TOPK; r += 256) {
        int wd = r >> 6;
        u64 word = aw[wd];
        if ((word >> (r & 63)) & 1ULL) {
            u32 rank = pfx[wd] + (u32)__popcll(word & ((1ULL << (r & 63)) - 1ULL));
            float sc = sscore[(size_t)b * TOPK + r];
            float4 bx = ((const float4*)sbox)[(size_t)b * TOPK + r];
            size_t base_o = (((size_t)b * 2 + 1) * TOPK + (size_t)rank) * 5;
            out[base_o + 0] = sc;
            out[base_o + 1] = bx.x;
            out[base_o + 2] = bx.y;
            out[base_o + 3] = bx.z;
            out[base_o + 4] = bx.w;
        }
    }
}

extern "C" void kernel_launch(void* const* d_in, const int* in_sizes, int n_in,
                              void* d_out, int out_size, void* d_ws, size_t ws_size,
                              hipStream_t stream) {
    const float* loc   = (const float*)d_in[0];
    const float* conf  = (const float*)d_in[1];
    const float* prior = (const float*)d_in[2];
    float* out = (float*)d_out;
    char* ws = (char*)d_ws;

    // ws layout (bytes) with lifetime-based aliasing into the mask region:
    //   mask    [0, 9216000)          transposed [b][w][i]; written by mask, read by sweep
    //   hist    [0, 4194304)          32*16*2048 u32 — dead after fused thresh
    //   binbase [4194304, 4456448)    32*2048 u32 — dead after rank_decode
    //   bincnt  [4456448, 4718592)    dead after rank_decode
    //   bpos    [4718592, 4980736)    bucket counters — dead after compact
    //   keys    [4980736, 5505024)    32*CAP u64 — dead after rank_decode
    //   tbin    [5505024, 5505152)    dead after compact
    //   ntotal  [5505152, 5505280)    dead after rank_decode
    //   skey    [5505280, 7602432)    32*16*512 u64 staged cands — dead after compact
    //   scnt    [7602432, 7604480)    32*16 u32 — dead after compact
    //   done    [7604480, 7604608)    32 u32 last-block counters — dead after hist
    //   sscore  [9216000, 9408000)
    //   sbox    [9408000, 10176000)   total 10,176,000 B
    u64* mask_buf = (u64*)(ws + 0);
    u32* hist     = (u32*)(ws + 0);
    u32* binbase  = (u32*)(ws + 4194304);
    u32* bincnt   = (u32*)(ws + 4456448);
    u32* bpos     = (u32*)(ws + 4718592);
    u64* keys     = (u64*)(ws + 4980736);
    int* tbin     = (int*)(ws + 5505024);
    u32* ntotal   = (u32*)(ws + 5505152);
    u64* skey     = (u64*)(ws + 5505280);
    u32* scnt     = (u32*)(ws + 7602432);
    u32* done     = (u32*)(ws + 7604480);
    float* sscore = (float*)(ws + 9216000);
    float* sbox   = (float*)(ws + 9408000);

    hipMemsetAsync(done, 0, NUM_B * sizeof(u32), stream);
    hist_kernel<<<dim3(HSLICES, 32), 256, 0, stream>>>((const float4*)conf, hist, bpos,
                                                       skey, scnt, done, tbin,
                                                       binbase, bincnt, ntotal);
    compact_kernel<<<dim3(150, 32), 256, 0, stream>>>((const float4*)conf, tbin, binbase,
                                                      bpos, keys, skey, scnt);
    rank_decode_kernel<<<dim3(CAP / 256, 32), 256, 0, stream>>>(keys, binbase, bincnt,
                                                                ntotal, loc, prior,
                                                                sscore, sbox);
    mask_kernel<<<dim3(NWORDS, NCHUNK, 32), 256, 0, stream>>>(sbox, mask_buf);
    sweep_kernel<<<32, 256, 0, stream>>>(mask_buf, sscore, sbox, out);
}

// Round 14
// 167.115 us; speedup vs baseline: 1.1402x; 1.1402x over previous
//
#include <hip/hip_runtime.h>
#include <stdint.h>

typedef unsigned long long u64;
typedef unsigned int u32;

#define NUM_B 32
#define NUM_P 76800
#define TOPK 1500
#define NBINS 2048   // linear bins: bin = min(int(s*2048), 2047); ~37.5 scores/bin
#define CAP 2048
#define NWORDS 24    // ceil(1500/64) u64 words per mask row == number of 64-row tiles
#define NCHUNK 6     // ceil(1500/256) row chunks for mask grid
#define HSLICES 16   // private histogram slices per batch (no global atomics)
#define HCHUNK (NUM_P / HSLICES)   // 4800 priors per slice
#define PB 1984      // prefilter bin for candidate staging (score ~0.96875)
#define SCAP 512     // per-(batch,slice) stage capacity (expected ~150; overflow->fallback)

__device__ __forceinline__ u32 fbits(float f) { return __float_as_uint(f); }
// Monotone non-decreasing in s => threshold-bin selection is order-correct,
// and cross-bin key order == bin order (floor is monotone).
__device__ __forceinline__ int binOf(float s) {
    int b = (int)(s * (float)NBINS);
    return (b > NBINS - 1) ? NBINS - 1 : b;
}
// wave-uniform lane read of a u64 register
__device__ __forceinline__ u64 readlane64(u64 v, int l) {
    u32 lo = (u32)__builtin_amdgcn_readlane((int)(u32)(v & 0xffffffffu), l);
    u32 hi = (u32)__builtin_amdgcn_readlane((int)(u32)(v >> 32), l);
    return ((u64)hi << 32) | lo;
}

// ---------------- histogram: LDS-private per (batch, slice); zeroes bucket ctrs;
// also stages candidates with bin >= PB so compact can skip re-reading conf ----------
__global__ __launch_bounds__(256) void hist_kernel(const float4* __restrict__ conf4,
                                                   u32* __restrict__ hist,
                                                   u32* __restrict__ bpos,
                                                   u64* __restrict__ skey,
                                                   u32* __restrict__ scnt) {
    int c = blockIdx.x, b = blockIdx.y, tid = threadIdx.x;
    // zero compact's per-(batch,bin) bucket counters: 2048/16 = 128 bins per block
    if (tid < NBINS / HSLICES) bpos[(size_t)b * NBINS + c * (NBINS / HSLICES) + tid] = 0;
    __shared__ u32 h[NBINS];
    __shared__ u64 stg[SCAP];
    __shared__ u32 sc_s;
    if (tid == 0) sc_s = 0;
    for (int i = tid; i < NBINS; i += 256) h[i] = 0;
    __syncthreads();
    const float4* base = conf4 + (size_t)b * (NUM_P / 2) + (size_t)c * (HCHUNK / 2);
    int pbase = c * HCHUNK;            // within-batch prior index base for this slice
    for (int i = tid; i < HCHUNK / 2; i += 256) {
        float4 v = base[i];            // 2 priors: (c0,c1,c0,c1); class-1 = .y/.w
        int p0 = pbase + i * 2;
        if (v.y > 0.01f) {
            int bn = binOf(v.y);
            atomicAdd(&h[bn], 1u);
            if (bn >= PB) {
                u32 s = atomicAdd(&sc_s, 1u);
                if (s < SCAP) stg[s] = ((u64)fbits(v.y) << 32) | (u32)(~p0);
            }
        }
        if (v.w > 0.01f) {
            int bn = binOf(v.w);
            atomicAdd(&h[bn], 1u);
            if (bn >= PB) {
                u32 s = atomicAdd(&sc_s, 1u);
                if (s < SCAP) stg[s] = ((u64)fbits(v.w) << 32) | (u32)(~(p0 + 1));
            }
        }
    }
    __syncthreads();
    u32* outp = hist + ((size_t)b * HSLICES + c) * NBINS;
    for (int i = tid; i < NBINS; i += 256) outp[i] = h[i];
    u32 n = sc_s;
    if (tid == 0) scnt[b * HSLICES + c] = n;   // raw (may exceed SCAP -> fallback)
    u64* sk = skey + (size_t)(b * HSLICES + c) * SCAP;
    u32 nn = (n < (u32)SCAP) ? n : (u32)SCAP;
    for (u32 i = tid; i < nn; i += 256) sk[i] = stg[i];
}

// ---------------- threshold + per-bin rank bases ----------------
// Finds smallest bin T with suffix count >= TOPK; additionally stores, for every
// bin in the processed (top) chunks: binbase[bin] = count of scores in bins > bin
// (= exact cross-bin rank base) and bincnt[bin] = count in bin. ntotal = candidates.
__global__ void thresh_kernel(const u32* __restrict__ hist, int* __restrict__ tbin,
                              u32* __restrict__ binbase, u32* __restrict__ bincnt,
                              u32* __restrict__ ntotal) {
    int b = blockIdx.x;
    int tid = threadIdx.x;
    const u32* hb = hist + (size_t)b * HSLICES * NBINS;
    __shared__ u32 vals[256];
    __shared__ int s_min;
    u32 total = 0;
    for (int c = 0; c < NBINS / 256; ++c) {
        if (tid == 0) s_min = 256;
        int bin = NBINS - 1 - (c * 256 + tid);
        u32 v = 0;
#pragma unroll
        for (int s = 0; s < HSLICES; ++s) v += hb[(size_t)s * NBINS + bin];
        __syncthreads();
        vals[tid] = v;
        __syncthreads();
        for (int off = 1; off < 256; off <<= 1) {
            u32 add = (tid >= off) ? vals[tid - off] : 0;
            __syncthreads();
            vals[tid] += add;
            __syncthreads();
        }
        u32 cum = total + vals[tid];          // inclusive suffix count down to `bin`
        binbase[(size_t)b * NBINS + bin] = cum - v;   // exclusive: bins strictly above
        bincnt [(size_t)b * NBINS + bin] = v;
        if (cum >= TOPK) atomicMin(&s_min, tid);
        __syncthreads();
        if (s_min < 256) {
            if (tid == s_min) { tbin[b] = bin; ntotal[b] = cum; }
            return;
        }
        total += vals[255];
    }
    if (tid == 0) { tbin[b] = 0; ntotal[b] = total; }
}

// ---------------- compact candidates into bin-grouped buckets ----------------
// Fast path (tbin >= PB, no stage overflow): read staged keys (~19 KB/batch) instead
// of re-scanning 19.7 MB of conf. Slow path: full conf scan (data-independent safety).
// keys land pre-grouped: bucket of bin bn occupies [binbase[bn], binbase[bn]+bincnt[bn]).
__global__ __launch_bounds__(256) void compact_kernel(
    const float4* __restrict__ conf4, const int* __restrict__ tbin,
    const u32* __restrict__ binbase, u32* __restrict__ bpos,
    u64* __restrict__ keys, const u64* __restrict__ skey,
    const u32* __restrict__ scnt) {
    int b = blockIdx.y;
    int tid = threadIdx.x;
    int tb = tbin[b];
    if (tb >= PB) {
        bool ovf = false;
#pragma unroll
        for (int s = 0; s < HSLICES; ++s) ovf |= (scnt[b * HSLICES + s] > (u32)SCAP);
        if (!ovf) {
            if (blockIdx.x >= HSLICES) return;
            int sl = blockIdx.x;
            u32 cnt = scnt[b * HSLICES + sl];
            const u64* sk = skey + (size_t)(b * HSLICES + sl) * SCAP;
            for (u32 i = tid; i < cnt; i += 256) {
                u64 key = sk[i];
                float sc = __uint_as_float((u32)(key >> 32));
                int bn = binOf(sc);
                if (bn >= tb) {
                    u32 slot = atomicAdd(&bpos[(size_t)b * NBINS + bn], 1u);
                    u32 pos = binbase[(size_t)b * NBINS + bn] + slot;
                    if (pos < CAP) keys[(size_t)b * CAP + pos] = key;
                }
            }
            return;
        }
    }
    // slow path: full conf scan
    int f4 = blockIdx.x * 256 + tid;            // float4 index within batch (2 priors)
    float4 c = conf4[(size_t)b * (NUM_P / 2) + f4];
    int p0 = f4 * 2, p1 = p0 + 1;
    int b0 = binOf(c.y);
    if (c.y > 0.01f && b0 >= tb) {
        u32 slot = atomicAdd(&bpos[(size_t)b * NBINS + b0], 1u);
        u32 pos = binbase[(size_t)b * NBINS + b0] + slot;
        if (pos < CAP) keys[(size_t)b * CAP + pos] = ((u64)fbits(c.y) << 32) | (u32)(~p0);
    }
    int b1 = binOf(c.w);
    if (c.w > 0.01f && b1 >= tb) {
        u32 slot = atomicAdd(&bpos[(size_t)b * NBINS + b1], 1u);
        u32 pos = binbase[(size_t)b * NBINS + b1] + slot;
        if (pos < CAP) keys[(size_t)b * CAP + pos] = ((u64)fbits(c.w) << 32) | (u32)(~p1);
    }
}

// ---------------- rank via bin base + small bucket scan, then gather+decode ----------
// rank(key) = binbase[bin(key)] + |{k in same bucket : k > key}|.  Cross-bin order is
// exact (bin order == score order; keys in higher bins are strictly greater).  Bucket
// is ~38 entries -> O(n * 38) total instead of O(n^2).  No LDS.
__global__ __launch_bounds__(256) void rank_decode_kernel(
    const u64* __restrict__ keys, const u32* __restrict__ binbase,
    const u32* __restrict__ bincnt, const u32* __restrict__ ntotal,
    const float* __restrict__ loc, const float* __restrict__ prior,
    float* __restrict__ sscore, float* __restrict__ sbox) {
#pragma clang fp contract(off)
    int b = blockIdx.y;
    int g = blockIdx.x * 256 + threadIdx.x;
    int n = (int)min(ntotal[b], (u32)CAP);
    if (g >= n) return;
    const u64* kb = keys + (size_t)b * CAP;
    u64 mykey = kb[g];
    float sc = __uint_as_float((u32)(mykey >> 32));
    int bn = binOf(sc);
    u32 start = binbase[(size_t)b * NBINS + bn];
    u32 end = start + bincnt[(size_t)b * NBINS + bn];
    if (end > (u32)n) end = (u32)n;
    u32 rank = start;
#pragma unroll 4
    for (u32 j = start; j < end; ++j) rank += (kb[j] > mykey) ? 1u : 0u;

    if (rank < TOPK) {
        u32 pidx = ~(u32)mykey;
        const float* lp = &loc[((size_t)b * NUM_P + pidx) * 4];
        const float* pp = &prior[(size_t)pidx * 4];
        float lx = lp[0], ly = lp[1], lw = lp[2], lh = lp[3];
        float pcx = pp[0], pcy = pp[1], pw = pp[2], ph = pp[3];
        float cx = pcx + (lx * 0.1f) * pw;
        float cy = pcy + (ly * 0.1f) * ph;
        float w  = pw * expf(lw * 0.2f);
        float h  = ph * expf(lh * 0.2f);
        float x1 = cx - w * 0.5f;
        float y1 = cy - h * 0.5f;
        float x2 = x1 + w;
        float y2 = y1 + h;
        sscore[(size_t)b * TOPK + rank] = sc;
        float* bx = &sbox[((size_t)b * TOPK + rank) * 4];
        bx[0] = x1; bx[1] = y1; bx[2] = x2; bx[3] = y2;
    }
}

// ---------------- NMS phase 1: suppression bitmask — transposed, balanced, div-free ----
// v10 layout: rows store words w > tile(i) as FORWARD suppression, and the diag
// slot (w == tile(i)) stores the BACKWARD column: bits j < i-in-word with
// iou(i,j) > thr.  By IoU symmetry C[l] bit i == forward M[i] bit l, so the sweep's
// ballot-walk over columns reproduces the exact greedy.  Slots with w < tile(i)
// remain unwritten and are provably never consumed.
__global__ __launch_bounds__(256) void mask_kernel(
    const float* __restrict__ sbox, u64* __restrict__ mask) {
#pragma clang fp contract(off)
    int w = blockIdx.x, c = blockIdx.y, b = blockIdx.z, tid = threadIdx.x;
    int i = c * 256 + tid;
    if ((w * 64 + 63) <= (c * 256)) return;   // whole chunk dead: no store at all
    __shared__ float4 cbox[64];
    __shared__ float car[64];
    if (tid < 64) {
        int j = w * 64 + tid;
        float4 bx = make_float4(0.f, 0.f, 0.f, 0.f);
        if (j < TOPK) bx = ((const float4*)sbox)[(size_t)b * TOPK + j];
        cbox[tid] = bx;
        car[tid] = (bx.z - bx.x) * (bx.w - bx.y);
    }
    __syncthreads();
    if (i < TOPK && (i >> 6) <= w) {
        const double MID = 0.5 * ((double)__uint_as_float(0x3E4CCCCDu) +
                                  (double)__uint_as_float(0x3E4CCCCEu));
        const float4 bx = ((const float4*)sbox)[(size_t)b * TOPK + i];
        float x1i = bx.x, y1i = bx.y, x2i = bx.z, y2i = bx.w;
        float ai = (x2i - x1i) * (y2i - y1i);
        u64 m = 0;
        for (int j2 = 0; j2 < 64; ++j2) {
            float4 cb = cbox[j2];
            float xx1 = fmaxf(cb.x, x1i);
            float yy1 = fmaxf(cb.y, y1i);
            float xx2 = fminf(cb.z, x2i);
            float yy2 = fminf(cb.w, y2i);
            float iw = fmaxf(xx2 - xx1, 0.0f);
            float ih = fmaxf(yy2 - yy1, 0.0f);
            float inter = iw * ih;
            float denom = (car[j2] + ai) - inter;
            if ((double)inter >= MID * (double)denom) m |= (1ULL << j2);
        }
        // diag word -> backward column (j < i in-word); off-diag (w > tile) -> full
        // word (all j there are > i globally).  (1<<0)-1 == 0 handles in-word row 0.
        u64 sel = ((i >> 6) == w) ? ((1ULL << (i - w * 64)) - 1ULL) : ~0ULL;
        mask[((size_t)b * NWORDS + w) * TOPK + i] = m & sel;
    }
}

// ---------------- NMS phase 2: producer/consumer sweep, one block (4 waves) per batch ----
// v10 sweep (measured best): wave 0 consumes from LDS; waves 1-3 stage 8 words
// each, triple-buffered, register-hop pipeline.  Greedy walk uses the BACKWARD
// column in the diag slot:
//   i = ffs(alive); kept |= bit i; alive &= ~bit i; alive &= ~ballot(col>>i & 1)
// — no per-iteration readlane of mask data.  Bit-exact greedy (IoU symmetry).
__global__ __launch_bounds__(256) void sweep_kernel(
    const u64* __restrict__ mask, const float* __restrict__ sscore,
    const float* __restrict__ sbox, float* __restrict__ out) {
    int b = blockIdx.x, tid = threadIdx.x;
    int lane = tid & 63, wid = tid >> 6;

    const u64* mbase = mask + (size_t)b * NWORDS * TOPK;   // word w, row r: mbase[w*TOPK+r]

    __shared__ u64 rowbuf[3][NWORDS][65];   // [slot][word][row(+pad)]
    __shared__ u64 aw[NWORDS];
    __shared__ u32 pfx[NWORDS + 1];

    u64 act = 0;
    u64 sv[8];
    if (wid == 0) {
        // initial active bitmap from validity (score > 0); lane w owns act word w
        for (int c = 0; c < NWORDS; ++c) {
            int r = c * 64 + lane;
            bool v = (r < TOPK) && (sscore[(size_t)b * TOPK + r] > 0.0f);
            u64 m = __ballot(v);
            if (lane == c) act = m;
        }
    } else {
        int w0 = (wid - 1) * 8;
        // stage tiles 0 and 1 (rows < 1500; only words w >= tile are valid in mem)
#pragma unroll
        for (int t = 0; t < 2; ++t) {
            u64 tmp[8];
#pragma unroll
            for (int k = 0; k < 8; ++k)
                tmp[k] = (w0 + k >= t) ? mbase[(size_t)(w0 + k) * TOPK + t * 64 + lane] : 0ULL;
#pragma unroll
            for (int k = 0; k < 8; ++k)
                rowbuf[t][w0 + k][lane] = tmp[k];
        }
        // issue loads for tile 2 into the register hop
        {
            int rr = 2 * 64 + lane;
#pragma unroll
            for (int k = 0; k < 8; ++k)
                sv[k] = (w0 + k >= 2) ? mbase[(size_t)(w0 + k) * TOPK + rr] : 0ULL;
        }
    }
    __syncthreads();

    for (int T = 0; T < NWORDS; ++T) {
        if (wid == 0) {
            // diag slot of tile T = BACKWARD column of row (T*64+lane)
            u64 col = rowbuf[T % 3][T][lane];
            u64 actw = readlane64(act, T);
            u64 alive = actw, kept = 0;
            while (alive) {
                int i2 = __ffsll(alive) - 1;
                kept |= (1ULL << i2);
                alive &= ~(1ULL << i2);
                u64 killm = __ballot(((col >> i2) & 1ULL) != 0ULL);
                alive &= ~killm;
            }
            if (lane == T) act = kept;
            // cross-tile apply: word lane of kept rows
            if (lane > T && lane < NWORDS) {
                u64 kb = kept;
                while (kb) {
                    int r = __ffsll(kb) - 1;
                    kb &= kb - 1;
                    act &= ~rowbuf[T % 3][lane][r];
                }
            }
        } else {
            int tw = T + 2;                 // tile whose data sits in sv (loaded last round)
            if (tw < NWORDS) {
                int w0 = (wid - 1) * 8;
#pragma unroll
                for (int k = 0; k < 8; ++k)
                    rowbuf[tw % 3][w0 + k][lane] = sv[k];
                int tn = T + 3;
                if (tn < NWORDS) {
                    int rr = tn * 64 + lane;
                    bool vr = rr < TOPK;
#pragma unroll
                    for (int k = 0; k < 8; ++k)
                        sv[k] = (vr && (w0 + k >= tn))
                                    ? mbase[(size_t)(w0 + k) * TOPK + rr] : 0ULL;
                }
            }
        }
        __syncthreads();
    }

    // epilogue: zero both output planes (exact float4 cover: 2*1500*5 = 15000 floats
    // = 3750 float4, base offset b*60000 B is 16B-aligned), then compact write
    if (wid == 0 && lane < NWORDS) aw[lane] = act;
    {
        float4* pz = (float4*)(out + (size_t)b * 2 * TOPK * 5);
        float4 z4 = make_float4(0.f, 0.f, 0.f, 0.f);
        for (int t = tid; t < (2 * TOPK * 5) / 4; t += 256) pz[t] = z4;
    }
    __syncthreads();
    if (tid == 0) {
        u32 acc = 0;
        for (int wd = 0; wd < NWORDS; ++wd) { pfx[wd] = acc; acc += (u32)__popcll(aw[wd]); }
        pfx[NWORDS] = acc;
    }
    __syncthreads();
    for (int r = tid; r < TOPK; r += 256) {
        int wd = r >> 6;
        u64 word = aw[wd];
        if ((word >> (r & 63)) & 1ULL) {
            u32 rank = pfx[wd] + (u32)__popcll(word & ((1ULL << (r & 63)) - 1ULL));
            float sc = sscore[(size_t)b * TOPK + r];
            float4 bx = ((const float4*)sbox)[(size_t)b * TOPK + r];
            size_t base_o = (((size_t)b * 2 + 1) * TOPK + (size_t)rank) * 5;
            out[base_o + 0] = sc;
            out[base_o + 1] = bx.x;
            out[base_o + 2] = bx.y;
            out[base_o + 3] = bx.z;
            out[base_o + 4] = bx.w;
        }
    }
}

extern "C" void kernel_launch(void* const* d_in, const int* in_sizes, int n_in,
                              void* d_out, int out_size, void* d_ws, size_t ws_size,
                              hipStream_t stream) {
    const float* loc   = (const float*)d_in[0];
    const float* conf  = (const float*)d_in[1];
    const float* prior = (const float*)d_in[2];
    float* out = (float*)d_out;
    char* ws = (char*)d_ws;

    // ws layout (bytes) with lifetime-based aliasing into the mask region:
    //   mask    [0, 9216000)          transposed [b][w][i]; written by mask, read by sweep
    //   hist    [0, 4194304)          32*16*2048 u32 — dead after thresh
    //   binbase [4194304, 4456448)    32*2048 u32 — dead after rank_decode
    //   bincnt  [4456448, 4718592)    dead after rank_decode
    //   bpos    [4718592, 4980736)    bucket counters — dead after compact
    //   keys    [4980736, 5505024)    32*CAP u64 — dead after rank_decode
    //   tbin    [5505024, 5505152)    dead after compact
    //   ntotal  [5505152, 5505280)    dead after rank_decode
    //   skey    [5505280, 7602432)    32*16*512 u64 staged cands — dead after compact
    //   scnt    [7602432, 7604480)    32*16 u32 — dead after compact
    //   sscore  [9216000, 9408000)
    //   sbox    [9408000, 10176000)   total 10,176,000 B
    u64* mask_buf = (u64*)(ws + 0);
    u32* hist     = (u32*)(ws + 0);
    u32* binbase  = (u32*)(ws + 4194304);
    u32* bincnt   = (u32*)(ws + 4456448);
    u32* bpos     = (u32*)(ws + 4718592);
    u64* keys     = (u64*)(ws + 4980736);
    int* tbin     = (int*)(ws + 5505024);
    u32* ntotal   = (u32*)(ws + 5505152);
    u64* skey     = (u64*)(ws + 5505280);
    u32* scnt     = (u32*)(ws + 7602432);
    float* sscore = (float*)(ws + 9216000);
    float* sbox   = (float*)(ws + 9408000);

    hist_kernel<<<dim3(HSLICES, 32), 256, 0, stream>>>((const float4*)conf, hist, bpos,
                                                       skey, scnt);
    thresh_kernel<<<32, 256, 0, stream>>>(hist, tbin, binbase, bincnt, ntotal);
    compact_kernel<<<dim3(150, 32), 256, 0, stream>>>((const float4*)conf, tbin, binbase,
                                                      bpos, keys, skey, scnt);
    rank_decode_kernel<<<dim3(CAP / 256, 32), 256, 0, stream>>>(keys, binbase, bincnt,
                                                                ntotal, loc, prior,
                                                                sscore, sbox);
    mask_kernel<<<dim3(NWORDS, NCHUNK, 32), 256, 0, stream>>>(sbox, mask_buf);
    sweep_kernel<<<32, 256, 0, stream>>>(mask_buf, sscore, sbox, out);
}